// Round 6
// baseline (571.890 us; speedup 1.0000x reference)
//
#include <hip/hip_runtime.h>
#include <hip/hip_fp16.h>
#include <cstdint>
#include <cstddef>

#define F_IN 128
#define HID 16
#define NBUK 256           // bucket = node >> 9
#define NPB  512           // nodes per bucket
#define CHUNK 8192         // edges per sort block

typedef float f4v __attribute__((ext_vector_type(4)));

// ---------------- index-width detection ----------------
// int64 little-endian with values < 2^31 => every odd 32-bit word of the
// first 64 entries is zero. Flag: 1 = int64, 0 = int32.
__global__ void k_detect(const int* __restrict__ eidx, int* __restrict__ flag) {
    if (blockIdx.x == 0 && threadIdx.x == 0) {
        int all0 = 1;
        for (int i = 0; i < 64; ++i) {
            if (eidx[2 * i + 1] != 0) { all0 = 0; break; }
        }
        *flag = all0;
    }
}

__device__ __forceinline__ int ld_idx(const int* __restrict__ p, int e, int is64) {
    return is64 ? p[2 * e] : p[e];
}
__device__ __forceinline__ int ld_idx_nt(const int* __restrict__ p, int e, int is64) {
    return is64 ? __builtin_nontemporal_load(&p[2 * e])
                : __builtin_nontemporal_load(&p[e]);
}

// ---------------- bucket histogram (LDS-staged, int atomics) ----------------
__launch_bounds__(256)
__global__ void k_bhist(const int* __restrict__ eidx, int E,
                        const int* __restrict__ flag, int* __restrict__ ghist) {
    __shared__ int lh[NBUK];
    int t = threadIdx.x;
    if (t < NBUK) lh[t] = 0;
    __syncthreads();
    int base = blockIdx.x * CHUNK;
    int cnt = min(CHUNK, E - base);
    int is64 = *flag;
    const int* colp = eidx + ((size_t)E << is64);
    for (int i = t; i < cnt; i += 256)
        atomicAdd(&lh[ld_idx_nt(colp, base + i, is64) >> 9], 1);
    __syncthreads();
    if (t < NBUK && lh[t]) atomicAdd(&ghist[t], lh[t]);
}

// ---------------- exact scan of 256 bucket counts ----------------
__global__ void k_bscan(const int* __restrict__ ghist, int E,
                        int* __restrict__ boff, int* __restrict__ gcur) {
    __shared__ int s[NBUK];
    int t = threadIdx.x;
    int v = ghist[t];
    s[t] = v;
    __syncthreads();
    for (int off = 1; off < NBUK; off <<= 1) {
        int a = (t >= off) ? s[t - off] : 0;
        __syncthreads();
        s[t] += a;
        __syncthreads();
    }
    int excl = s[t] - v;
    boff[t] = excl;
    gcur[t] = excl;
    if (t == NBUK - 1) boff[NBUK] = E;
}

// ------- bucket scatter: LDS cursor per bucket; 32-edge runs share L2 lines -------
// pairs[k] = r | (c&511)<<20, grouped by bucket (c>>9)
__launch_bounds__(256)
__global__ void k_bscatter(const int* __restrict__ eidx, int E,
                           const int* __restrict__ flag,
                           int* __restrict__ gcur, uint32_t* __restrict__ pairs) {
    __shared__ int lh[NBUK];
    __shared__ int lcur[NBUK];
    int t = threadIdx.x;
    if (t < NBUK) lh[t] = 0;
    __syncthreads();
    int base = blockIdx.x * CHUNK;
    int cnt = min(CHUNK, E - base);
    int is64 = *flag;
    const int* rowp = eidx;
    const int* colp = eidx + ((size_t)E << is64);
    for (int i = t; i < cnt; i += 256)
        atomicAdd(&lh[ld_idx_nt(colp, base + i, is64) >> 9], 1);
    __syncthreads();
    if (t < NBUK) {
        int c = lh[t];
        lcur[t] = c ? atomicAdd(&gcur[t], c) : 0;   // reserve contiguous run
    }
    __syncthreads();
    for (int i = t; i < cnt; i += 256) {
        int c = ld_idx_nt(colp, base + i, is64);
        int r = ld_idx_nt(rowp, base + i, is64);
        int buk = c >> 9;
        int pos = atomicAdd(&lcur[buk], 1);
        pairs[pos] = (uint32_t)r | ((uint32_t)(c & (NPB - 1)) << 20);
    }
}

// ------- per-bucket counting sort -> per-node CSR (srcs, noff) + dinv -------
__launch_bounds__(512)
__global__ void k_bsort(const uint32_t* __restrict__ pairs, const int* __restrict__ boff,
                        int* __restrict__ srcs, int* __restrict__ noff,
                        float* __restrict__ dinv, int n) {
    __shared__ int cnt[NPB];
    __shared__ int scn[NPB];
    int t = threadIdx.x;   // 0..511
    int b = blockIdx.x;
    cnt[t] = 0;
    __syncthreads();
    int beg = boff[b], end = boff[b + 1];
    for (int k = beg + t; k < end; k += 512)
        atomicAdd(&cnt[pairs[k] >> 20], 1);
    __syncthreads();
    scn[t] = cnt[t];
    __syncthreads();
    for (int off = 1; off < NPB; off <<= 1) {
        int v = (t >= off) ? scn[t - off] : 0;
        __syncthreads();
        scn[t] += v;
        __syncthreads();
    }
    int node = b * NPB + t;
    int excl = scn[t] - cnt[t];
    if (node <= n) noff[node] = beg + excl;      // node==n lands here (last bucket)
    if (node < n)  dinv[node] = rsqrtf((float)cnt[t] + 1.0f);
    cnt[t] = beg + excl;                         // reuse as cursor
    __syncthreads();
    for (int k = beg + t; k < end; k += 512) {
        uint32_t p = pairs[k];
        int pos = atomicAdd(&cnt[p >> 20], 1);
        srcs[pos] = (int)(p & 0xFFFFF);
    }
}

// ------- hs1 = (x @ W1) * dinv[row], fp16 ----------------
__launch_bounds__(256)
__global__ void k_gemm1(const float* __restrict__ x, const float* __restrict__ W1,
                        const float* __restrict__ dinv, __half* __restrict__ hs, int n) {
    __shared__ float Wt[16 * 132];
    for (int i = threadIdx.x; i < F_IN * HID; i += 256) {
        int k = i >> 4, j = i & 15;
        Wt[j * 132 + k] = W1[i];
    }
    __syncthreads();
    int row = blockIdx.x * 16 + (threadIdx.x >> 4);
    int j = threadIdx.x & 15;
    if (row >= n) return;
    const f4v* xr = (const f4v*)(x + (size_t)row * F_IN);
    float acc = 0.f;
#pragma unroll
    for (int kk = 0; kk < 32; ++kk) {
        f4v xv = __builtin_nontemporal_load(&xr[kk]);   // stream: don't pollute L2
        float4 wv = *(const float4*)&Wt[j * 132 + 4 * kk];
        acc += xv.x * wv.x + xv.y * wv.y + xv.z * wv.z + xv.w * wv.w;
    }
    hs[(size_t)row * HID + j] = __float2half(acc * dinv[row]);
}

// ------- fused GCN layer: CSR gather, register accumulate -------
// Each 16-lane group owns one node i; lane j owns feature j.
// acc = hs[i][j] + sum_{r in N(i)} hs[r][j]        (hs pre-scaled by dinv[src])
// hrelu[j] = relu(acc * dinv[i] + bias[j])
// EPI 0: out0 = fp16( (hrelu @ Wnext) * dinv )     (next layer's hs)
// EPI 1: out0 = fp16( hrelu )                      (h2 for the edge MLP)
// NOTE: n % 16 == 0 (100000): no partial groups, uniform barriers.
template <int EPI>
__launch_bounds__(256)
__global__ void k_layer(const int* __restrict__ srcs, const int* __restrict__ noff,
                        const __half* __restrict__ hs, const float* __restrict__ dinv,
                        const float* __restrict__ bias, const float* __restrict__ Wnext,
                        __half* __restrict__ out0) {
    __shared__ float Ws[256];
    __shared__ float bs[16];
    __shared__ float srow[16 * 17];
    int t = threadIdx.x;
    if (EPI == 0) { if (t < 256) Ws[t] = Wnext[t]; }
    if (t < 16) bs[t] = bias[t];
    __syncthreads();

    int i = blockIdx.x * 16 + (t >> 4);    // node
    int j = t & 15;                        // feature
    int beg = noff[i], end = noff[i + 1];
    float acc = __half2float(hs[(size_t)i * HID + j]);   // self-loop term

    int kb = beg;
    for (; kb + 16 <= end; kb += 16) {
        int idx = __builtin_nontemporal_load(&srcs[kb + j]);   // coalesced stream
#pragma unroll
        for (int m = 0; m < 16; ++m) {
            int r = __shfl(idx, m, 16);    // broadcast within the 16-lane group
            acc += __half2float(hs[(size_t)r * HID + j]);
        }
    }
    if (kb < end) {
        int lim = end - kb;
        int idx = srcs[kb + ((j < lim) ? j : (lim - 1))];
        for (int m = 0; m < lim; ++m) {
            int r = __shfl(idx, m, 16);
            acc += __half2float(hs[(size_t)r * HID + j]);
        }
    }

    float di = dinv[i];
    float hrelu = fmaxf(acc * di + bs[j], 0.f);
    if (EPI == 1) {
        out0[(size_t)i * HID + j] = __float2half(hrelu);
        return;
    }
    int ln = t >> 4;
    srow[ln * 17 + j] = hrelu;
    __syncthreads();
    float a0 = 0.f;
#pragma unroll
    for (int k = 0; k < 16; ++k) a0 += srow[ln * 17 + k] * Ws[k * 16 + j];
    out0[(size_t)i * HID + j] = __float2half(a0 * di);
}

// ------- per-edge MLP from h2 gathers (3.2 MB, L2-resident) + log_softmax -------
// z = relu(A^T h2[r] + B^T h2[c] + b1);  logits = W2^T z + b2;  out = log_softmax
// 2 edges per thread (e, e+Eh) amortize the LDS weight broadcasts.
__launch_bounds__(256)
__global__ void k_edge(const int* __restrict__ eidx, int E, const int* __restrict__ flag,
                       const __half* __restrict__ h2, const float* __restrict__ fc1W,
                       const float* __restrict__ fc1b, const float* __restrict__ fc2W,
                       const float* __restrict__ fc2b, float* __restrict__ out) {
    __shared__ float2 WS[256];     // A rows (0..127), B rows (128..255), float2 pairs
    __shared__ float2 b1s[8];
    __shared__ float W2s[32], b2s[2];
    int t = threadIdx.x;
    WS[t] = ((const float2*)fc1W)[t];   // exactly 256 float2 = 512 floats
    if (t < 8)  b1s[t] = ((const float2*)fc1b)[t];
    if (t < 32) W2s[t] = fc2W[t];
    if (t < 2)  b2s[t] = fc2b[t];
    __syncthreads();

    int Eh = (E + 1) >> 1;
    int e0 = blockIdx.x * 256 + t;
    if (e0 >= Eh) return;
    int e1 = e0 + Eh;
    bool has1 = (e1 < E);
    int is64 = *flag;
    const int* rowp = eidx;
    const int* colp = eidx + ((size_t)E << is64);
    int r0 = ld_idx_nt(rowp, e0, is64), c0 = ld_idx_nt(colp, e0, is64);
    int r1 = has1 ? ld_idx_nt(rowp, e1, is64) : r0;
    int c1 = has1 ? ld_idx_nt(colp, e1, is64) : c0;

    const uint4* p;
    p = (const uint4*)(h2 + (size_t)r0 * HID); uint4 A0 = p[0], A1 = p[1];
    p = (const uint4*)(h2 + (size_t)c0 * HID); uint4 B0 = p[0], B1 = p[1];
    p = (const uint4*)(h2 + (size_t)r1 * HID); uint4 C0 = p[0], C1 = p[1];
    p = (const uint4*)(h2 + (size_t)c1 * HID); uint4 D0 = p[0], D1 = p[1];

    float fr0[16], fc0[16], fr1[16], fc1v[16];
#define UNP(dst, X, Y) { float2 u_;                                         \
    u_ = __half22float2(*(__half2*)&X.x); dst[0] = u_.x; dst[1] = u_.y;     \
    u_ = __half22float2(*(__half2*)&X.y); dst[2] = u_.x; dst[3] = u_.y;     \
    u_ = __half22float2(*(__half2*)&X.z); dst[4] = u_.x; dst[5] = u_.y;     \
    u_ = __half22float2(*(__half2*)&X.w); dst[6] = u_.x; dst[7] = u_.y;     \
    u_ = __half22float2(*(__half2*)&Y.x); dst[8] = u_.x; dst[9] = u_.y;     \
    u_ = __half22float2(*(__half2*)&Y.y); dst[10] = u_.x; dst[11] = u_.y;   \
    u_ = __half22float2(*(__half2*)&Y.z); dst[12] = u_.x; dst[13] = u_.y;   \
    u_ = __half22float2(*(__half2*)&Y.w); dst[14] = u_.x; dst[15] = u_.y; }
    UNP(fr0, A0, A1) UNP(fc0, B0, B1) UNP(fr1, C0, C1) UNP(fc1v, D0, D1)
#undef UNP

    float2 z0[8], z1[8];
#pragma unroll
    for (int m = 0; m < 8; ++m) { z0[m] = b1s[m]; z1[m] = b1s[m]; }
#pragma unroll
    for (int k = 0; k < 16; ++k) {
        float ar0 = fr0[k], ac0 = fc0[k], ar1 = fr1[k], ac1 = fc1v[k];
#pragma unroll
        for (int m = 0; m < 8; ++m) {
            float2 wa = WS[k * 8 + m], wb = WS[128 + k * 8 + m];
            z0[m].x += ar0 * wa.x + ac0 * wb.x;
            z0[m].y += ar0 * wa.y + ac0 * wb.y;
            z1[m].x += ar1 * wa.x + ac1 * wb.x;
            z1[m].y += ar1 * wa.y + ac1 * wb.y;
        }
    }

#define FIN(zarr, ee) {                                                     \
    float l0 = b2s[0], l1 = b2s[1];                                         \
    _Pragma("unroll")                                                       \
    for (int m = 0; m < 8; ++m) {                                           \
        float zx = fmaxf(zarr[m].x, 0.f), zy = fmaxf(zarr[m].y, 0.f);       \
        l0 += zx * W2s[4 * m]     + zy * W2s[4 * m + 2];                    \
        l1 += zx * W2s[4 * m + 1] + zy * W2s[4 * m + 3];                    \
    }                                                                       \
    float mm = fmaxf(l0, l1);                                               \
    float ex0 = __expf(l0 - mm), ex1 = __expf(l1 - mm);                     \
    float lse = mm + __logf(ex0 + ex1);                                     \
    float* op = out + 2 * (size_t)(ee);                                     \
    __builtin_nontemporal_store(l0 - lse, op);                              \
    __builtin_nontemporal_store(l1 - lse, op + 1); }
    FIN(z0, e0)
    if (has1) FIN(z1, e1)
#undef FIN
}

static inline size_t rnd4(size_t v) { return (v + 3) & ~(size_t)3; }

extern "C" void kernel_launch(void* const* d_in, const int* in_sizes, int n_in,
                              void* d_out, int out_size, void* d_ws, size_t ws_size,
                              hipStream_t stream) {
    const float* x    = (const float*)d_in[0];
    const int*   eidx = (const int*)d_in[1];
    const float* W1   = (const float*)d_in[2];
    const float* b1   = (const float*)d_in[3];
    const float* W2   = (const float*)d_in[4];
    const float* b2   = (const float*)d_in[5];
    const float* fc1W = (const float*)d_in[6];
    const float* fc1b = (const float*)d_in[7];
    const float* fc2W = (const float*)d_in[8];
    const float* fc2b = (const float*)d_in[9];

    const int n = in_sizes[0] / F_IN;   // 100000 (divisible by 16)
    const int E = in_sizes[1] / 2;      // 3200000
    const int NBLK_SORT = (E + CHUNK - 1) / CHUNK;   // 391
    const int NBLK_BUK  = (n + NPB - 1) / NPB;       // 196

    // workspace carve-up (float units, 16B-aligned regions)
    float* ws = (float*)d_ws;
    size_t a = 0;
    float*    dinv  = ws + a;              a += rnd4(n);
    uint32_t* pairs = (uint32_t*)(ws + a); a += rnd4(E);
    int*      srcs  = (int*)(ws + a);      a += rnd4(E);
    int*      noff  = (int*)(ws + a);      a += rnd4(n + 1);
    int*      boff  = (int*)(ws + a);      a += rnd4(NBUK + 1);
    int*      gcur  = (int*)(ws + a);      a += NBUK;
    int*      ghist = (int*)(ws + a);      a += NBUK;
    int*      flag  = (int*)(ws + a);      a += 4;
    __half*   hs1   = (__half*)(ws + a);   a += rnd4((size_t)n * HID / 2);
    __half*   hs2   = (__half*)(ws + a);   a += rnd4((size_t)n * HID / 2);
    __half*   h2b   = (__half*)(ws + a);   a += rnd4((size_t)n * HID / 2);
    float* out = (float*)d_out;

    k_detect<<<1, 64, 0, stream>>>(eidx, flag);

    // ---- two-level bucket sort -> per-node CSR (shared by both layers) ----
    hipMemsetAsync(ghist, 0, NBUK * sizeof(int), stream);
    k_bhist<<<NBLK_SORT, 256, 0, stream>>>(eidx, E, flag, ghist);
    k_bscan<<<1, NBUK, 0, stream>>>(ghist, E, boff, gcur);
    k_bscatter<<<NBLK_SORT, 256, 0, stream>>>(eidx, E, flag, gcur, pairs);
    k_bsort<<<NBLK_BUK, 512, 0, stream>>>(pairs, boff, srcs, noff, dinv, n);

    // ---- dense prologue: hs1 = (x@W1)*dinv (fp16) ----
    k_gemm1<<<(n + 15) / 16, 256, 0, stream>>>(x, W1, dinv, hs1, n);

    // ---- layer 1 (epilogue: hs2 = relu(gcn)@W2 * dinv, fp16) ----
    k_layer<0><<<n / 16, 256, 0, stream>>>(srcs, noff, hs1, dinv, b1, W2, hs2);
    // ---- layer 2 (plain relu output h2, fp16) ----
    k_layer<1><<<n / 16, 256, 0, stream>>>(srcs, noff, hs2, dinv, b2, nullptr, h2b);
    // ---- edge MLP + log_softmax (gathers h2: 3.2 MB, fits per-XCD L2) ----
    {
        int Eh = (E + 1) >> 1;
        k_edge<<<(Eh + 255) / 256, 256, 0, stream>>>(eidx, E, flag, h2b,
                                                     fc1W, fc1b, fc2W, fc2b, out);
    }
}

// Round 8
// 325.736 us; speedup vs baseline: 1.7557x; 1.7557x over previous
//
#include <hip/hip_runtime.h>
#include <hip/hip_fp16.h>
#include <cstdint>
#include <cstddef>

#define F_IN 128
#define HID 16
#define NBUK 256           // bucket = node >> 9
#define NPB  512           // nodes per bucket
#define CHUNK 8192         // edges per sort block

typedef float f4v __attribute__((ext_vector_type(4)));
typedef float f2v __attribute__((ext_vector_type(2)));
typedef int   i2v __attribute__((ext_vector_type(2)));

// ---------------- index-width detection ----------------
// int64 little-endian with values < 2^31 => every odd 32-bit word of the
// first 64 entries is zero. Flag: 1 = int64, 0 = int32.
__global__ void k_detect(const int* __restrict__ eidx, int* __restrict__ flag) {
    if (blockIdx.x == 0 && threadIdx.x == 0) {
        int all0 = 1;
        for (int i = 0; i < 64; ++i) {
            if (eidx[2 * i + 1] != 0) { all0 = 0; break; }
        }
        *flag = all0;
    }
}

__device__ __forceinline__ int ld_idx_nt(const int* __restrict__ p, int e, int is64) {
    return is64 ? __builtin_nontemporal_load(&p[2 * e])
                : __builtin_nontemporal_load(&p[e]);
}

// ---------------- bucket histogram (LDS-staged, int atomics) ----------------
__launch_bounds__(256)
__global__ void k_bhist(const int* __restrict__ eidx, int E,
                        const int* __restrict__ flag, int* __restrict__ ghist) {
    __shared__ int lh[NBUK];
    int t = threadIdx.x;
    if (t < NBUK) lh[t] = 0;
    __syncthreads();
    int base = blockIdx.x * CHUNK;
    int cnt = min(CHUNK, E - base);
    int is64 = *flag;
    const int* colp = eidx + ((size_t)E << is64);
    for (int i = t; i < cnt; i += 256)
        atomicAdd(&lh[ld_idx_nt(colp, base + i, is64) >> 9], 1);
    __syncthreads();
    if (t < NBUK && lh[t]) atomicAdd(&ghist[t], lh[t]);
}

// ---------------- exact scan of 256 bucket counts ----------------
__global__ void k_bscan(const int* __restrict__ ghist, int E,
                        int* __restrict__ boff, int* __restrict__ gcur) {
    __shared__ int s[NBUK];
    int t = threadIdx.x;
    int v = ghist[t];
    s[t] = v;
    __syncthreads();
    for (int off = 1; off < NBUK; off <<= 1) {
        int a = (t >= off) ? s[t - off] : 0;
        __syncthreads();
        s[t] += a;
        __syncthreads();
    }
    int excl = s[t] - v;
    boff[t] = excl;
    gcur[t] = excl;
    if (t == NBUK - 1) boff[NBUK] = E;
}

// ------- bucket scatter: LDS cursor per bucket; 32-edge runs share L2 lines -------
// pairs[k] = r | (c&511)<<20, grouped by bucket (c>>9)
// Also emits compacted epack[e] = (r, c) for the edge-MLP pass (if non-null).
__launch_bounds__(256)
__global__ void k_bscatter(const int* __restrict__ eidx, int E,
                           const int* __restrict__ flag,
                           int* __restrict__ gcur, uint32_t* __restrict__ pairs,
                           i2v* __restrict__ epack) {
    __shared__ int lh[NBUK];
    __shared__ int lcur[NBUK];
    int t = threadIdx.x;
    if (t < NBUK) lh[t] = 0;
    __syncthreads();
    int base = blockIdx.x * CHUNK;
    int cnt = min(CHUNK, E - base);
    int is64 = *flag;
    const int* rowp = eidx;
    const int* colp = eidx + ((size_t)E << is64);
    for (int i = t; i < cnt; i += 256)
        atomicAdd(&lh[ld_idx_nt(colp, base + i, is64) >> 9], 1);
    __syncthreads();
    if (t < NBUK) {
        int c = lh[t];
        lcur[t] = c ? atomicAdd(&gcur[t], c) : 0;   // reserve contiguous run
    }
    __syncthreads();
    for (int i = t; i < cnt; i += 256) {
        int e = base + i;
        int c = ld_idx_nt(colp, e, is64);
        int r = ld_idx_nt(rowp, e, is64);
        if (epack) {
            i2v pk; pk.x = r; pk.y = c;
            __builtin_nontemporal_store(pk, &epack[e]);
        }
        int buk = c >> 9;
        int pos = atomicAdd(&lcur[buk], 1);
        pairs[pos] = (uint32_t)r | ((uint32_t)(c & (NPB - 1)) << 20);
    }
}

// ------- per-bucket counting sort -> per-node CSR (srcs, noff) + dinv -------
__launch_bounds__(512)
__global__ void k_bsort(const uint32_t* __restrict__ pairs, const int* __restrict__ boff,
                        int* __restrict__ srcs, int* __restrict__ noff,
                        float* __restrict__ dinv, int n) {
    __shared__ int cnt[NPB];
    __shared__ int scn[NPB];
    int t = threadIdx.x;   // 0..511
    int b = blockIdx.x;
    cnt[t] = 0;
    __syncthreads();
    int beg = boff[b], end = boff[b + 1];
    for (int k = beg + t; k < end; k += 512)
        atomicAdd(&cnt[pairs[k] >> 20], 1);
    __syncthreads();
    scn[t] = cnt[t];
    __syncthreads();
    for (int off = 1; off < NPB; off <<= 1) {
        int v = (t >= off) ? scn[t - off] : 0;
        __syncthreads();
        scn[t] += v;
        __syncthreads();
    }
    int node = b * NPB + t;
    int excl = scn[t] - cnt[t];
    if (node <= n) noff[node] = beg + excl;      // node==n lands here (last bucket)
    if (node < n)  dinv[node] = rsqrtf((float)cnt[t] + 1.0f);
    cnt[t] = beg + excl;                         // reuse as cursor
    __syncthreads();
    for (int k = beg + t; k < end; k += 512) {
        uint32_t p = pairs[k];
        int pos = atomicAdd(&cnt[p >> 20], 1);
        srcs[pos] = (int)(p & 0xFFFFF);
    }
}

// ------- hs1 = (x @ W1) * dinv[row], fp16 ----------------
__launch_bounds__(256)
__global__ void k_gemm1(const float* __restrict__ x, const float* __restrict__ W1,
                        const float* __restrict__ dinv, __half* __restrict__ hs, int n) {
    __shared__ float Wt[16 * 132];
    for (int i = threadIdx.x; i < F_IN * HID; i += 256) {
        int k = i >> 4, j = i & 15;
        Wt[j * 132 + k] = W1[i];
    }
    __syncthreads();
    int row = blockIdx.x * 16 + (threadIdx.x >> 4);
    int j = threadIdx.x & 15;
    if (row >= n) return;
    const f4v* xr = (const f4v*)(x + (size_t)row * F_IN);
    float acc = 0.f;
#pragma unroll
    for (int kk = 0; kk < 32; ++kk) {
        f4v xv = __builtin_nontemporal_load(&xr[kk]);   // stream: don't pollute L2
        float4 wv = *(const float4*)&Wt[j * 132 + 4 * kk];
        acc += xv.x * wv.x + xv.y * wv.y + xv.z * wv.z + xv.w * wv.w;
    }
    hs[(size_t)row * HID + j] = __float2half(acc * dinv[row]);
}

// ------- fused GCN layer: CSR gather, register accumulate -------
// Each 16-lane group owns one node i; lane j owns feature j.
// acc = hs[i][j] + sum_{r in N(i)} hs[r][j]        (hs pre-scaled by dinv[src])
// hrelu[j] = relu(acc * dinv[i] + bias[j])
// EPI 0: out0 = fp16( (hrelu @ Wnext) * dinv )     (next layer's hs)
// EPI 1: out0 = fp16(hrelu @ Wnext[0:16]) = u, out1 = ...[16:32] = v
// NOTE: n % 16 == 0 (100000): no partial groups, uniform barriers.
template <int EPI>
__launch_bounds__(256)
__global__ void k_layer(const int* __restrict__ srcs, const int* __restrict__ noff,
                        const __half* __restrict__ hs, const float* __restrict__ dinv,
                        const float* __restrict__ bias, const float* __restrict__ Wnext,
                        __half* __restrict__ out0, __half* __restrict__ out1) {
    __shared__ float Ws[512];
    __shared__ float bs[16];
    __shared__ float srow[16 * 17];
    int t = threadIdx.x;
    int nw = (EPI == 0) ? 256 : 512;
    for (int i = t; i < nw; i += 256) Ws[i] = Wnext[i];
    if (t < 16) bs[t] = bias[t];
    __syncthreads();

    int i = blockIdx.x * 16 + (t >> 4);    // node
    int j = t & 15;                        // feature
    int beg = noff[i], end = noff[i + 1];
    float acc = __half2float(hs[(size_t)i * HID + j]);   // self-loop term

    int kb = beg;
    for (; kb + 16 <= end; kb += 16) {
        int idx = __builtin_nontemporal_load(&srcs[kb + j]);   // coalesced stream
#pragma unroll
        for (int m = 0; m < 16; ++m) {
            int r = __shfl(idx, m, 16);    // broadcast within the 16-lane group
            acc += __half2float(hs[(size_t)r * HID + j]);
        }
    }
    if (kb < end) {
        int lim = end - kb;
        int idx = srcs[kb + ((j < lim) ? j : (lim - 1))];
        for (int m = 0; m < lim; ++m) {
            int r = __shfl(idx, m, 16);
            acc += __half2float(hs[(size_t)r * HID + j]);
        }
    }

    float di = dinv[i];
    float hrelu = fmaxf(acc * di + bs[j], 0.f);
    int ln = t >> 4;
    srow[ln * 17 + j] = hrelu;
    __syncthreads();
    float a0 = 0.f, a1 = 0.f;
#pragma unroll
    for (int k = 0; k < 16; ++k) {
        float hv = srow[ln * 17 + k];
        a0 += hv * Ws[k * 16 + j];
        if (EPI == 1) a1 += hv * Ws[(16 + k) * 16 + j];
    }
    if (EPI == 0) {
        out0[(size_t)i * HID + j] = __float2half(a0 * di);
    } else {
        out0[(size_t)i * HID + j] = __float2half(a0);
        out1[(size_t)i * HID + j] = __float2half(a1);
    }
}

// ---------------- per-edge MLP + log_softmax (fp16 u,v gathers) ----------------
// R5-proven structure: 1 edge/thread, ~36 VGPR, no big local arrays.
template <int USE_EPACK>
__launch_bounds__(256)
__global__ void k_edge(const int* __restrict__ eidx, const i2v* __restrict__ epack,
                       int E, const int* __restrict__ flag,
                       const __half* __restrict__ u, const __half* __restrict__ v,
                       const float* __restrict__ fc1b, const float* __restrict__ fc2W,
                       const float* __restrict__ fc2b, float* __restrict__ out) {
    __shared__ float b1s[16], W2s[32], b2s[2];
    if (threadIdx.x < 16) b1s[threadIdx.x] = fc1b[threadIdx.x];
    if (threadIdx.x < 32) W2s[threadIdx.x] = fc2W[threadIdx.x];
    if (threadIdx.x < 2) b2s[threadIdx.x] = fc2b[threadIdx.x];
    __syncthreads();
    int e = blockIdx.x * blockDim.x + threadIdx.x;
    if (e >= E) return;
    int r, c;
    if (USE_EPACK) {
        i2v pk = __builtin_nontemporal_load(&epack[e]);
        r = pk.x; c = pk.y;
    } else {
        int is64 = *flag;
        const int* rowp = eidx;
        const int* colp = eidx + ((size_t)E << is64);
        r = ld_idx_nt(rowp, e, is64);
        c = ld_idx_nt(colp, e, is64);
    }
    const uint4* up = (const uint4*)(u + (size_t)r * HID);
    const uint4* vp = (const uint4*)(v + (size_t)c * HID);
    uint4 U0 = up[0], U1 = up[1], V0 = vp[0], V1 = vp[1];
    float l0 = b2s[0], l1 = b2s[1];
#define PROC(uw, vw, jb)                                                        \
    {                                                                           \
        float2 fu = __half22float2(*(__half2*)&(uw));                           \
        float2 fv = __half22float2(*(__half2*)&(vw));                           \
        float z = fmaxf(fu.x + fv.x + b1s[jb], 0.f);                            \
        l0 += z * W2s[2 * (jb)]; l1 += z * W2s[2 * (jb) + 1];                   \
        z = fmaxf(fu.y + fv.y + b1s[(jb) + 1], 0.f);                            \
        l0 += z * W2s[2 * (jb) + 2]; l1 += z * W2s[2 * (jb) + 3];               \
    }
    PROC(U0.x, V0.x, 0) PROC(U0.y, V0.y, 2) PROC(U0.z, V0.z, 4) PROC(U0.w, V0.w, 6)
    PROC(U1.x, V1.x, 8) PROC(U1.y, V1.y, 10) PROC(U1.z, V1.z, 12) PROC(U1.w, V1.w, 14)
#undef PROC
    float m = fmaxf(l0, l1);
    float e0 = __expf(l0 - m), e1 = __expf(l1 - m);
    float lse = m + __logf(e0 + e1);
    f2v res; res.x = l0 - lse; res.y = l1 - lse;
    __builtin_nontemporal_store(res, &((f2v*)out)[e]);
}

static inline size_t rnd4(size_t v) { return (v + 3) & ~(size_t)3; }

extern "C" void kernel_launch(void* const* d_in, const int* in_sizes, int n_in,
                              void* d_out, int out_size, void* d_ws, size_t ws_size,
                              hipStream_t stream) {
    const float* x    = (const float*)d_in[0];
    const int*   eidx = (const int*)d_in[1];
    const float* W1   = (const float*)d_in[2];
    const float* b1   = (const float*)d_in[3];
    const float* W2   = (const float*)d_in[4];
    const float* b2   = (const float*)d_in[5];
    const float* fc1W = (const float*)d_in[6];
    const float* fc1b = (const float*)d_in[7];
    const float* fc2W = (const float*)d_in[8];
    const float* fc2b = (const float*)d_in[9];

    const int n = in_sizes[0] / F_IN;   // 100000 (divisible by 16)
    const int E = in_sizes[1] / 2;      // 3200000
    const int NBLK_SORT = (E + CHUNK - 1) / CHUNK;   // 391
    const int NBLK_BUK  = (n + NPB - 1) / NPB;       // 196

    // workspace carve-up (float units, 16B-aligned regions)
    float* ws = (float*)d_ws;
    size_t a = 0;
    float*    dinv  = ws + a;              a += rnd4(n);
    uint32_t* pairs = (uint32_t*)(ws + a); a += rnd4(E);
    int*      srcs  = (int*)(ws + a);      a += rnd4(E);
    int*      noff  = (int*)(ws + a);      a += rnd4(n + 1);
    int*      boff  = (int*)(ws + a);      a += rnd4(NBUK + 1);
    int*      gcur  = (int*)(ws + a);      a += NBUK;
    int*      ghist = (int*)(ws + a);      a += NBUK;
    int*      flag  = (int*)(ws + a);      a += 4;
    __half*   hs1   = (__half*)(ws + a);   a += rnd4((size_t)n * HID / 2);
    __half*   hs2   = (__half*)(ws + a);   a += rnd4((size_t)n * HID / 2);
    __half*   ubuf  = (__half*)(ws + a);   a += rnd4((size_t)n * HID / 2);
    __half*   vbuf  = (__half*)(ws + a);   a += rnd4((size_t)n * HID / 2);
    // optional compacted edge list (25.6 MB) — only if workspace allows
    bool use_epack = ws_size >= (a + 2 * (size_t)E + 8) * sizeof(float);
    i2v* epack = use_epack ? (i2v*)(ws + a) : nullptr;
    float* out = (float*)d_out;

    k_detect<<<1, 64, 0, stream>>>(eidx, flag);

    // ---- two-level bucket sort -> per-node CSR (shared by both layers) ----
    (void)hipMemsetAsync(ghist, 0, NBUK * sizeof(int), stream);
    k_bhist<<<NBLK_SORT, 256, 0, stream>>>(eidx, E, flag, ghist);
    k_bscan<<<1, NBUK, 0, stream>>>(ghist, E, boff, gcur);
    k_bscatter<<<NBLK_SORT, 256, 0, stream>>>(eidx, E, flag, gcur, pairs, epack);
    k_bsort<<<NBLK_BUK, 512, 0, stream>>>(pairs, boff, srcs, noff, dinv, n);

    // ---- dense prologue: hs1 = (x@W1)*dinv (fp16) ----
    k_gemm1<<<(n + 15) / 16, 256, 0, stream>>>(x, W1, dinv, hs1, n);

    // ---- layer 1 (epilogue: hs2 = relu(gcn)@W2 * dinv, fp16) ----
    k_layer<0><<<n / 16, 256, 0, stream>>>(srcs, noff, hs1, dinv, b1, W2, hs2, nullptr);
    // ---- layer 2 (epilogue: u,v = relu(gcn)@fc1W halves, fp16) ----
    k_layer<1><<<n / 16, 256, 0, stream>>>(srcs, noff, hs2, dinv, b2, fc1W, ubuf, vbuf);
    // ---- edge MLP + log_softmax ----
    if (use_epack)
        k_edge<1><<<(E + 255) / 256, 256, 0, stream>>>(eidx, epack, E, flag, ubuf, vbuf,
                                                       fc1b, fc2W, fc2b, out);
    else
        k_edge<0><<<(E + 255) / 256, 256, 0, stream>>>(eidx, epack, E, flag, ubuf, vbuf,
                                                       fc1b, fc2W, fc2b, out);
}

// Round 9
// 315.733 us; speedup vs baseline: 1.8113x; 1.0317x over previous
//
#include <hip/hip_runtime.h>
#include <hip/hip_fp16.h>
#include <cstdint>
#include <cstddef>

#define F_IN 128
#define HID 16
#define NBUK 1024          // bucket = node >> 7
#define NPB  128           // nodes per bucket
#define CHUNK 8192         // edges per histogram block
#define CHUNK2 16384       // edges per scatter block (16-edge runs = 64B lines)

typedef float f4v __attribute__((ext_vector_type(4)));
typedef float f2v __attribute__((ext_vector_type(2)));
typedef int   i2v __attribute__((ext_vector_type(2)));
typedef int   i4v __attribute__((ext_vector_type(4)));

// ---------------- index-width detection ----------------
// int64 little-endian with values < 2^31 => every odd 32-bit word of the
// first 64 entries is zero. Flag: 1 = int64, 0 = int32.
__global__ void k_detect(const int* __restrict__ eidx, int* __restrict__ flag) {
    if (blockIdx.x == 0 && threadIdx.x == 0) {
        int all0 = 1;
        for (int i = 0; i < 64; ++i) {
            if (eidx[2 * i + 1] != 0) { all0 = 0; break; }
        }
        *flag = all0;
    }
}

__device__ __forceinline__ int ld_idx_nt(const int* __restrict__ p, int e, int is64) {
    return is64 ? __builtin_nontemporal_load(&p[2 * e])
                : __builtin_nontemporal_load(&p[e]);
}

// ---------------- bucket histogram (LDS-staged, int atomics) ----------------
__launch_bounds__(256)
__global__ void k_bhist(const int* __restrict__ eidx, int E,
                        const int* __restrict__ flag, int* __restrict__ ghist) {
    __shared__ int lh[NBUK];
    int t = threadIdx.x;
    for (int i = t; i < NBUK; i += 256) lh[i] = 0;
    __syncthreads();
    int base = blockIdx.x * CHUNK;
    int cnt = min(CHUNK, E - base);
    int is64 = *flag;
    const int* colp = eidx + ((size_t)E << is64);
    for (int i = t; i < cnt; i += 256)
        atomicAdd(&lh[ld_idx_nt(colp, base + i, is64) >> 7], 1);
    __syncthreads();
    for (int i = t; i < NBUK; i += 256)
        if (lh[i]) atomicAdd(&ghist[i], lh[i]);
}

// ---------------- exact scan of 1024 bucket counts (single block) ----------------
__global__ void k_bscan(const int* __restrict__ ghist, int E,
                        int* __restrict__ boff, int* __restrict__ gcur) {
    __shared__ int s[NBUK];
    int t = threadIdx.x;
    int v = ghist[t];
    s[t] = v;
    __syncthreads();
    for (int off = 1; off < NBUK; off <<= 1) {
        int a = (t >= off) ? s[t - off] : 0;
        __syncthreads();
        s[t] += a;
        __syncthreads();
    }
    int excl = s[t] - v;
    boff[t] = excl;
    gcur[t] = excl;
    if (t == NBUK - 1) boff[NBUK] = E;
}

// ------- bucket scatter: LDS cursor per bucket; 16-edge runs = full L2 lines -------
// pairs[k] = r | (c&127)<<20, grouped by bucket (c>>7)
__launch_bounds__(512)
__global__ void k_bscatter(const int* __restrict__ eidx, int E,
                           const int* __restrict__ flag,
                           int* __restrict__ gcur, uint32_t* __restrict__ pairs) {
    __shared__ int lh[NBUK];
    __shared__ int lcur[NBUK];
    int t = threadIdx.x;
    for (int i = t; i < NBUK; i += 512) lh[i] = 0;
    __syncthreads();
    int base = blockIdx.x * CHUNK2;
    int cnt = min(CHUNK2, E - base);
    int is64 = *flag;
    const int* rowp = eidx;
    const int* colp = eidx + ((size_t)E << is64);
    for (int i = t; i < cnt; i += 512)
        atomicAdd(&lh[ld_idx_nt(colp, base + i, is64) >> 7], 1);
    __syncthreads();
    for (int i = t; i < NBUK; i += 512) {
        int c = lh[i];
        lcur[i] = c ? atomicAdd(&gcur[i], c) : 0;   // reserve contiguous run
    }
    __syncthreads();
    for (int i = t; i < cnt; i += 512) {
        int e = base + i;
        int c = ld_idx_nt(colp, e, is64);
        int r = ld_idx_nt(rowp, e, is64);
        int buk = c >> 7;
        int pos = atomicAdd(&lcur[buk], 1);
        pairs[pos] = (uint32_t)r | ((uint32_t)(c & (NPB - 1)) << 20);
    }
}

// ------- per-bucket counting sort -> per-node CSR (srcs, noff) + dinv -------
__launch_bounds__(256)
__global__ void k_bsort(const uint32_t* __restrict__ pairs, const int* __restrict__ boff,
                        int* __restrict__ srcs, int* __restrict__ noff,
                        float* __restrict__ dinv, int n) {
    __shared__ int cnt[NPB];
    __shared__ int scn[NPB];
    int t = threadIdx.x;
    int b = blockIdx.x;
    if (t < NPB) cnt[t] = 0;
    __syncthreads();
    int beg = boff[b], end = boff[b + 1];
    for (int k = beg + t; k < end; k += 256)
        atomicAdd(&cnt[pairs[k] >> 20], 1);
    __syncthreads();
    if (t < NPB) scn[t] = cnt[t];
    __syncthreads();
    for (int off = 1; off < NPB; off <<= 1) {
        int v = 0;
        if (t < NPB && t >= off) v = scn[t - off];
        __syncthreads();
        if (t < NPB) scn[t] += v;
        __syncthreads();
    }
    if (t < NPB) {
        int node = b * NPB + t;
        int excl = scn[t] - cnt[t];
        if (node <= n) noff[node] = beg + excl;      // node==n lands here (last bucket)
        if (node < n)  dinv[node] = rsqrtf((float)cnt[t] + 1.0f);
        cnt[t] = beg + excl;                         // reuse as cursor
    }
    __syncthreads();
    for (int k = beg + t; k < end; k += 256) {
        uint32_t p = pairs[k];
        int pos = atomicAdd(&cnt[p >> 20], 1);
        srcs[pos] = (int)(p & 0xFFFFF);
    }
}

// ------- hs1 = (x @ W1) * dinv[row], fp16 ----------------
__launch_bounds__(256)
__global__ void k_gemm1(const float* __restrict__ x, const float* __restrict__ W1,
                        const float* __restrict__ dinv, __half* __restrict__ hs, int n) {
    __shared__ float Wt[16 * 132];
    for (int i = threadIdx.x; i < F_IN * HID; i += 256) {
        int k = i >> 4, j = i & 15;
        Wt[j * 132 + k] = W1[i];
    }
    __syncthreads();
    int row = blockIdx.x * 16 + (threadIdx.x >> 4);
    int j = threadIdx.x & 15;
    if (row >= n) return;
    const f4v* xr = (const f4v*)(x + (size_t)row * F_IN);
    float acc = 0.f;
#pragma unroll
    for (int kk = 0; kk < 32; ++kk) {
        f4v xv = __builtin_nontemporal_load(&xr[kk]);   // stream: don't pollute L2
        float4 wv = *(const float4*)&Wt[j * 132 + 4 * kk];
        acc += xv.x * wv.x + xv.y * wv.y + xv.z * wv.z + xv.w * wv.w;
    }
    hs[(size_t)row * HID + j] = __float2half(acc * dinv[row]);
}

// ------- fused GCN layer: CSR gather, register accumulate -------
// Each 16-lane group owns one node i; lane j owns feature j.
// acc = hs[i][j] + sum_{r in N(i)} hs[r][j]        (hs pre-scaled by dinv[src])
// hrelu[j] = relu(acc * dinv[i] + bias[j])
// EPI 0: out0 = fp16( (hrelu @ Wnext) * dinv )     (next layer's hs)
// EPI 1: out0 = fp16(hrelu @ Wnext[0:16]) = u, out1 = ...[16:32] = v
// NOTE: n % 16 == 0 (100000): no partial groups, uniform barriers.
template <int EPI>
__launch_bounds__(256)
__global__ void k_layer(const int* __restrict__ srcs, const int* __restrict__ noff,
                        const __half* __restrict__ hs, const float* __restrict__ dinv,
                        const float* __restrict__ bias, const float* __restrict__ Wnext,
                        __half* __restrict__ out0, __half* __restrict__ out1) {
    __shared__ float Ws[512];
    __shared__ float bs[16];
    __shared__ float srow[16 * 17];
    int t = threadIdx.x;
    int nw = (EPI == 0) ? 256 : 512;
    for (int i = t; i < nw; i += 256) Ws[i] = Wnext[i];
    if (t < 16) bs[t] = bias[t];
    __syncthreads();

    int i = blockIdx.x * 16 + (t >> 4);    // node
    int j = t & 15;                        // feature
    int beg = noff[i], end = noff[i + 1];
    float acc = __half2float(hs[(size_t)i * HID + j]);   // self-loop term

    int kb = beg;
    for (; kb + 16 <= end; kb += 16) {
        int idx = __builtin_nontemporal_load(&srcs[kb + j]);   // coalesced stream
#pragma unroll
        for (int m = 0; m < 16; ++m) {
            int r = __shfl(idx, m, 16);    // broadcast within the 16-lane group
            acc += __half2float(hs[(size_t)r * HID + j]);
        }
    }
    if (kb < end) {
        int lim = end - kb;
        int idx = srcs[kb + ((j < lim) ? j : (lim - 1))];
        for (int m = 0; m < lim; ++m) {
            int r = __shfl(idx, m, 16);
            acc += __half2float(hs[(size_t)r * HID + j]);
        }
    }

    float di = dinv[i];
    float hrelu = fmaxf(acc * di + bs[j], 0.f);
    int ln = t >> 4;
    srow[ln * 17 + j] = hrelu;
    __syncthreads();
    float a0 = 0.f, a1 = 0.f;
#pragma unroll
    for (int k = 0; k < 16; ++k) {
        float hv = srow[ln * 17 + k];
        a0 += hv * Ws[k * 16 + j];
        if (EPI == 1) a1 += hv * Ws[(16 + k) * 16 + j];
    }
    if (EPI == 0) {
        out0[(size_t)i * HID + j] = __float2half(a0 * di);
    } else {
        out0[(size_t)i * HID + j] = __float2half(a0);
        out1[(size_t)i * HID + j] = __float2half(a1);
    }
}

// ---------------- per-edge MLP + log_softmax (fp16 u,v gathers) ----------------
// 2 adjacent edges per thread: vector index loads, 8 gathers in flight,
// coalesced float4 output. Lean register footprint (~70 VGPR, no arrays).
__launch_bounds__(256)
__global__ void k_edge(const int* __restrict__ eidx, int E,
                       const int* __restrict__ flag,
                       const __half* __restrict__ u, const __half* __restrict__ v,
                       const float* __restrict__ fc1b, const float* __restrict__ fc2W,
                       const float* __restrict__ fc2b, float* __restrict__ out) {
    __shared__ float b1s[16], W2s[32], b2s[2];
    if (threadIdx.x < 16) b1s[threadIdx.x] = fc1b[threadIdx.x];
    if (threadIdx.x < 32) W2s[threadIdx.x] = fc2W[threadIdx.x];
    if (threadIdx.x < 2) b2s[threadIdx.x] = fc2b[threadIdx.x];
    __syncthreads();
    int g = blockIdx.x * blockDim.x + threadIdx.x;   // edge-pair id
    int e0 = 2 * g;
    if (e0 >= E) return;
    bool has1 = (e0 + 1 < E);
    int is64 = *flag;
    const int* rowp = eidx;
    const int* colp = eidx + ((size_t)E << is64);
    int r0, c0, r1, c1;
    if (is64) {   // e0 even -> 16B aligned
        i4v rw = __builtin_nontemporal_load((const i4v*)(rowp + 2 * (size_t)e0));
        i4v cw = __builtin_nontemporal_load((const i4v*)(colp + 2 * (size_t)e0));
        r0 = rw.x; r1 = rw.z; c0 = cw.x; c1 = cw.z;
    } else {      // e0 even -> 8B aligned
        i2v rw = __builtin_nontemporal_load((const i2v*)(rowp + e0));
        i2v cw = __builtin_nontemporal_load((const i2v*)(colp + e0));
        r0 = rw.x; r1 = rw.y; c0 = cw.x; c1 = cw.y;
    }
    if (!has1) { r1 = r0; c1 = c0; }
    // issue all 8 gathers before any math (MLP hides under them)
    const uint4* p0 = (const uint4*)(u + (size_t)r0 * HID);
    const uint4* q0 = (const uint4*)(v + (size_t)c0 * HID);
    const uint4* p1 = (const uint4*)(u + (size_t)r1 * HID);
    const uint4* q1 = (const uint4*)(v + (size_t)c1 * HID);
    uint4 U0a = p0[0], U0b = p0[1], V0a = q0[0], V0b = q0[1];
    uint4 U1a = p1[0], U1b = p1[1], V1a = q1[0], V1b = q1[1];

#define PROC(l0, l1, uw, vw, jb)                                                \
    {                                                                           \
        float2 fu = __half22float2(*(__half2*)&(uw));                           \
        float2 fv = __half22float2(*(__half2*)&(vw));                           \
        float z = fmaxf(fu.x + fv.x + b1s[jb], 0.f);                            \
        l0 += z * W2s[2 * (jb)]; l1 += z * W2s[2 * (jb) + 1];                   \
        z = fmaxf(fu.y + fv.y + b1s[(jb) + 1], 0.f);                            \
        l0 += z * W2s[2 * (jb) + 2]; l1 += z * W2s[2 * (jb) + 3];               \
    }
    float a0 = b2s[0], a1 = b2s[1];
    PROC(a0, a1, U0a.x, V0a.x, 0) PROC(a0, a1, U0a.y, V0a.y, 2)
    PROC(a0, a1, U0a.z, V0a.z, 4) PROC(a0, a1, U0a.w, V0a.w, 6)
    PROC(a0, a1, U0b.x, V0b.x, 8) PROC(a0, a1, U0b.y, V0b.y, 10)
    PROC(a0, a1, U0b.z, V0b.z, 12) PROC(a0, a1, U0b.w, V0b.w, 14)
    float b0 = b2s[0], b1v = b2s[1];
    PROC(b0, b1v, U1a.x, V1a.x, 0) PROC(b0, b1v, U1a.y, V1a.y, 2)
    PROC(b0, b1v, U1a.z, V1a.z, 4) PROC(b0, b1v, U1a.w, V1a.w, 6)
    PROC(b0, b1v, U1b.x, V1b.x, 8) PROC(b0, b1v, U1b.y, V1b.y, 10)
    PROC(b0, b1v, U1b.z, V1b.z, 12) PROC(b0, b1v, U1b.w, V1b.w, 14)
#undef PROC
    float m0 = fmaxf(a0, a1);
    float lse0 = m0 + __logf(__expf(a0 - m0) + __expf(a1 - m0));
    float m1 = fmaxf(b0, b1v);
    float lse1 = m1 + __logf(__expf(b0 - m1) + __expf(b1v - m1));
    if (has1) {
        f4v res; res.x = a0 - lse0; res.y = a1 - lse0;
        res.z = b0 - lse1; res.w = b1v - lse1;
        __builtin_nontemporal_store(res, (f4v*)(out + 2 * (size_t)e0));
    } else {
        f2v res; res.x = a0 - lse0; res.y = a1 - lse0;
        __builtin_nontemporal_store(res, (f2v*)(out + 2 * (size_t)e0));
    }
}

static inline size_t rnd4(size_t v) { return (v + 3) & ~(size_t)3; }

extern "C" void kernel_launch(void* const* d_in, const int* in_sizes, int n_in,
                              void* d_out, int out_size, void* d_ws, size_t ws_size,
                              hipStream_t stream) {
    const float* x    = (const float*)d_in[0];
    const int*   eidx = (const int*)d_in[1];
    const float* W1   = (const float*)d_in[2];
    const float* b1   = (const float*)d_in[3];
    const float* W2   = (const float*)d_in[4];
    const float* b2   = (const float*)d_in[5];
    const float* fc1W = (const float*)d_in[6];
    const float* fc1b = (const float*)d_in[7];
    const float* fc2W = (const float*)d_in[8];
    const float* fc2b = (const float*)d_in[9];

    const int n = in_sizes[0] / F_IN;   // 100000 (divisible by 16)
    const int E = in_sizes[1] / 2;      // 3200000
    const int NBLK_HIST = (E + CHUNK - 1) / CHUNK;     // 391
    const int NBLK_SCAT = (E + CHUNK2 - 1) / CHUNK2;   // 196
    const int NBLK_BUK  = (n + NPB - 1) / NPB;         // 782

    // workspace carve-up (float units, 16B-aligned regions)
    float* ws = (float*)d_ws;
    size_t a = 0;
    float*    dinv  = ws + a;              a += rnd4(n);
    uint32_t* pairs = (uint32_t*)(ws + a); a += rnd4(E);
    int*      srcs  = (int*)(ws + a);      a += rnd4(E);
    int*      noff  = (int*)(ws + a);      a += rnd4(n + 1);
    int*      boff  = (int*)(ws + a);      a += rnd4(NBUK + 1);
    int*      gcur  = (int*)(ws + a);      a += NBUK;
    int*      ghist = (int*)(ws + a);      a += NBUK;
    int*      flag  = (int*)(ws + a);      a += 4;
    __half*   hs1   = (__half*)(ws + a);   a += rnd4((size_t)n * HID / 2);
    __half*   hs2   = (__half*)(ws + a);   a += rnd4((size_t)n * HID / 2);
    __half*   ubuf  = (__half*)(ws + a);   a += rnd4((size_t)n * HID / 2);
    __half*   vbuf  = (__half*)(ws + a);   a += rnd4((size_t)n * HID / 2);
    float* out = (float*)d_out;

    k_detect<<<1, 64, 0, stream>>>(eidx, flag);

    // ---- two-level bucket sort -> per-node CSR (shared by both layers) ----
    (void)hipMemsetAsync(ghist, 0, NBUK * sizeof(int), stream);
    k_bhist<<<NBLK_HIST, 256, 0, stream>>>(eidx, E, flag, ghist);
    k_bscan<<<1, NBUK, 0, stream>>>(ghist, E, boff, gcur);
    k_bscatter<<<NBLK_SCAT, 512, 0, stream>>>(eidx, E, flag, gcur, pairs);
    k_bsort<<<NBLK_BUK, 256, 0, stream>>>(pairs, boff, srcs, noff, dinv, n);

    // ---- dense prologue: hs1 = (x@W1)*dinv (fp16) ----
    k_gemm1<<<(n + 15) / 16, 256, 0, stream>>>(x, W1, dinv, hs1, n);

    // ---- layer 1 (epilogue: hs2 = relu(gcn)@W2 * dinv, fp16) ----
    k_layer<0><<<n / 16, 256, 0, stream>>>(srcs, noff, hs1, dinv, b1, W2, hs2, nullptr);
    // ---- layer 2 (epilogue: u,v = relu(gcn)@fc1W halves, fp16) ----
    k_layer<1><<<n / 16, 256, 0, stream>>>(srcs, noff, hs2, dinv, b2, fc1W, ubuf, vbuf);
    // ---- edge MLP + log_softmax (2 edges/thread) ----
    {
        int npair = (E + 1) / 2;
        k_edge<<<(npair + 255) / 256, 256, 0, stream>>>(eidx, E, flag, ubuf, vbuf,
                                                        fc1b, fc2W, fc2b, out);
    }
}